// Round 9
// baseline (355.648 us; speedup 1.0000x reference)
//
#include <hip/hip_runtime.h>
#include <hip/hip_bf16.h>

typedef unsigned short u16;
typedef __bf16 bf16x8 __attribute__((ext_vector_type(8)));
typedef _Float16 f16x8 __attribute__((ext_vector_type(8)));
typedef unsigned short u16x8 __attribute__((ext_vector_type(8)));
typedef float f32x4 __attribute__((ext_vector_type(4)));

#define SQHF 0.70710678118654752440f

__device__ __forceinline__ u16 f2bf(float f) {
  __hip_bfloat16 h = __float2bfloat16(f);
  return __builtin_bit_cast(u16, h);
}
__device__ __forceinline__ float bf2f(u16 u) {
  unsigned x = ((unsigned)u) << 16;
  return __builtin_bit_cast(float, x);
}
__device__ __forceinline__ void split2(float v, u16& hi, u16& lo) {
  hi = f2bf(v);
  lo = f2bf(v - bf2f(hi));
}

template <int N>
__device__ __forceinline__ void vmwait() {
  asm volatile("s_waitcnt vmcnt(%0)" ::"i"(N) : "memory");
}

// async global->LDS, 16B per lane; LDS dest is wave-uniform base + lane*16
__device__ __forceinline__ void gload_lds16(const void* g, void* l) {
  __builtin_amdgcn_global_load_lds(
      (const __attribute__((address_space(1))) unsigned int*)g,
      (__attribute__((address_space(3))) unsigned int*)l, 16, 0, 0);
}

__device__ __forceinline__ float block_sum(float v) {
#pragma unroll
  for (int o = 32; o; o >>= 1) v += __shfl_xor(v, o);
  __shared__ float red[4];
  if ((threadIdx.x & 63) == 0) red[threadIdx.x >> 6] = v;
  __syncthreads();
  return red[0] + red[1] + red[2] + red[3];
}

// weight-norm of in_v rows (dim E over C), store TRANSPOSED split pair Wt[c][e]
__global__ void wnorm_t_kernel(const float* __restrict__ v, const float* __restrict__ g,
                               u16* __restrict__ wth, u16* __restrict__ wtl) {
  const int e = blockIdx.x;
  const float* vr = v + (long)e * 1024;
  float ss = 0.f;
  for (int c = threadIdx.x; c < 1024; c += 256) { float t = vr[c]; ss += t * t; }
  const float tot = block_sum(ss);
  const float scl = g[e] / sqrtf(tot);
  for (int c = threadIdx.x; c < 1024; c += 256) {
    u16 hi, lo;
    split2(vr[c] * scl, hi, lo);
    wth[(long)c * 1024 + e] = hi;
    wtl[(long)c * 1024 + e] = lo;
  }
}

// weight-norm of out_v rows (dim C over E), natural layout single bf16 (A for Zo GEMM)
__global__ void wnorm_kernel(const float* __restrict__ v, const float* __restrict__ g,
                             u16* __restrict__ w) {
  const int c = blockIdx.x;
  const float* vr = v + (long)c * 1024;
  float ss = 0.f;
  for (int e = threadIdx.x; e < 1024; e += 256) { float t = vr[e]; ss += t * t; }
  const float tot = block_sum(ss);
  const float scl = g[c] / sqrtf(tot);
  for (int e = threadIdx.x; e < 1024; e += 256) w[(long)c * 1024 + e] = f2bf(vr[e] * scl);
}

// conv_feats [B,1024,196] -> y_t bf16 split pair [32][256][1024] (for Zi GEMM / rc / Zo)
// and y_t f16 single into concat cols 1024..2047 (for f16 scores GEMM).
// Rows v in [196,256) are zero.
__global__ void prep_y_kernel(const float* __restrict__ conv, u16* __restrict__ bth,
                              u16* __restrict__ btl, u16* __restrict__ concat) {
  const int b = blockIdx.x >> 4;
  const int e0 = (blockIdx.x & 15) << 6;
  __shared__ float tile[64 * 224];
  const float* cb = conv + ((long)b * 1024 + e0) * 196;
  for (int idx = threadIdx.x; idx < 64 * 224; idx += 256) {
    const int rr = idx / 224, vv = idx - rr * 224;
    tile[idx] = (vv < 196) ? cb[(long)rr * 196 + vv] : 0.f;
  }
  __syncthreads();
  for (int idx = threadIdx.x; idx < 256 * 64; idx += 256) {
    const int vr = idx >> 6, c = idx & 63;
    const float val = (vr < 224) ? tile[c * 224 + vr] : 0.f;
    u16 hi, lo;
    split2(val, hi, lo);
    const long o = ((long)b * 256 + vr) * 1024 + e0 + c;
    bth[o] = hi;
    btl[o] = lo;
    const _Float16 hf = (_Float16)val;  // RNE
    concat[((long)b * 256 + vr) * 2048 + 1024 + e0 + c] = __builtin_bit_cast(u16, hf);
  }
}

// rc[b][v] = sum_e in_b[e] * y[b,e,v], from transposed split y (coalesced over e)
__global__ void rc_kernel(const float* __restrict__ in_b, const u16* __restrict__ bth,
                          const u16* __restrict__ btl, float* __restrict__ rc) {
  const int b = blockIdx.x / 49;
  const int v = (blockIdx.x % 49) * 4 + (threadIdx.x >> 6);
  const int lane = threadIdx.x & 63;
  const long base = ((long)b * 256 + v) * 1024;
  float acc = 0.f;
  for (int e = lane; e < 1024; e += 64)
    acc += in_b[e] * (bf2f(bth[base + e]) + bf2f(btl[base + e]));
#pragma unroll
  for (int o = 32; o; o >>= 1) acc += __shfl_xor(acc, o);
  if (lane == 0) rc[b * 256 + v] = acc;
}

// scores = s0+s1 (K-split halves) +rc, *sqrt(1/2) -> attn f32 [M][196] + attn bf16 [M][256]
__global__ void softmax_kernel(const float* __restrict__ s0b, const float* __restrict__ s1b,
                               const float* __restrict__ rc,
                               float* __restrict__ attn, u16* __restrict__ attn_bf) {
  const long row = (long)blockIdx.x * 4 + (threadIdx.x >> 6);
  const int lane = threadIdx.x & 63;
  const int b = (int)(row >> 10);
  const float* s0 = s0b + row * 256;
  const float* s1 = s1b + row * 256;
  const float* rcb = rc + b * 256;
  float v0 = (s0[lane] + s1[lane] + rcb[lane]) * SQHF;
  float v1 = (s0[64 + lane] + s1[64 + lane] + rcb[64 + lane]) * SQHF;
  float v2 = (s0[128 + lane] + s1[128 + lane] + rcb[128 + lane]) * SQHF;
  float v3 = (lane < 4) ? (s0[192 + lane] + s1[192 + lane] + rcb[192 + lane]) * SQHF : -1e30f;
  float mx = fmaxf(fmaxf(v0, v1), fmaxf(v2, v3));
#pragma unroll
  for (int o = 32; o; o >>= 1) mx = fmaxf(mx, __shfl_xor(mx, o));
  const float e0 = __expf(v0 - mx), e1 = __expf(v1 - mx), e2 = __expf(v2 - mx);
  const float e3 = (lane < 4) ? __expf(v3 - mx) : 0.f;
  float sm = e0 + e1 + e2 + e3;
#pragma unroll
  for (int o = 32; o; o >>= 1) sm += __shfl_xor(sm, o);
  const float inv = 1.f / sm;
  float* arow = attn + row * 196;
  arow[lane] = e0 * inv;
  arow[64 + lane] = e1 * inv;
  arow[128 + lane] = e2 * inv;
  if (lane < 4) arow[192 + lane] = e3 * inv;
  u16* brow = attn_bf + row * 256;
  brow[lane] = f2bf(e0 * inv);
  brow[64 + lane] = f2bf(e1 * inv);
  brow[128 + lane] = f2bf(e2 * inv);
  brow[192 + lane] = (lane < 4) ? f2bf(e3 * inv) : (u16)0;
}

// 128x128-tile MFMA GEMM, B^T-layout operands. ALL modes use the T4
// counted-vmcnt pipeline (R8-validated): per step {stage(ahead); vmcnt(N)
// waits only the batch needed NOW; s_barrier; compute; s_barrier} — no
// vmcnt(0) drain in steady state.
//   MODE 0: single-bf16, DEPTH=2, 4 loads/stage -> vmcnt(4).
//   MODE 1: 3-term split-bf16, DEPTH=2, 8 loads/stage -> vmcnt(8).
//   MODE 2: fp16 single (A staged f32 XOR-swizzled, cvt in-reg; B f16),
//     DEPTH=3 (R8 post-mortem: 2-deep left ~600cy/step HBM-latency stall on
//     the streamed A operand; 3 buffers give each batch 2 iterations to land),
//     6 loads/stage -> vmcnt(12), tail 6 -> 0.
// bf16/f16 LDS tiles use chunk-XOR swizzle (row>>1)&3 on both stage-src and read.
// kSplit2: grid doubled; half=bid&1 selects K-half (kOff=half*1024), EPI3 target.
// EPI: 1=(acc+bias[col]+extra[row*1024+col])*scale -> f32
//      2=f2bf(acc*scale) -> bf16; 3=acc -> f32 (out1/out2 by half)
//      6=(_Float16)acc -> f16
// NOTE: NO min-waves clause in launch_bounds (R3: (256,4)->spills; R4: (256,2)
// ->84 VGPR, lost ILP). Compiler free choice is the proven regime.
template <int EPI, int MODE>
__global__ __launch_bounds__(256) void gemm128(
    const u16* __restrict__ Ah, const u16* __restrict__ Al,
    const float* __restrict__ Af0, const float* __restrict__ Af1, int kSw,
    const u16* __restrict__ Bh, const u16* __restrict__ Bl,
    int N, int K, int ldA, int ldB, int ldOut,
    int mTilesPerBatch, long bStride, int aTilesMod, int kSplit2,
    const float* __restrict__ bias, const float* __restrict__ extra,
    float scale, void* __restrict__ out1, void* __restrict__ out2) {
  constexpr int SPLIT = (MODE == 1);
  constexpr int AF16 = (MODE == 2);
  constexpr int DEPTH = AF16 ? 3 : 2;
  constexpr int LPS = (MODE == 0) ? 4 : (MODE == 1 ? 8 : 6);  // loads per stage
  // LDS u16-slot layout per buffer:
  //  MODE0: A@0[4096] B@4096[4096]            HSM 8192  (x2 = 32KB)
  //  MODE1: Ah@0 Al@4096 Bh@8192 Bl@12288     HSM 16384 (x2 = 64KB)
  //  MODE2: Af32@0[8192] B@8192[4096]         HSM 12288 (x3 = 72KB)
  constexpr int TAL = 4096;
  constexpr int TBH = (MODE == 0) ? 4096 : 8192;
  constexpr int TBL = 12288;
  constexpr int HSM = (MODE == 0) ? 8192 : (MODE == 1 ? 16384 : 12288);
  __shared__ __align__(16) u16 smem[HSM * DEPTH];

  int bid = blockIdx.x, nwg = gridDim.x, half = 0;
  if (kSplit2) { half = bid & 1; bid >>= 1; nwg >>= 1; }
  const int kOff = half << 10;

  const int numN = N >> 7;
  const int q = nwg >> 3, r = nwg & 7, xcd = bid & 7, l8 = bid >> 3;
  const int wg = (xcd < r ? xcd * (q + 1) : r * (q + 1) + (xcd - r) * q) + l8;
  const int mTile = wg / numN, nTile = wg - mTile * numN;
  const long rowBase = (long)mTile << 7;
  const int colBase = nTile << 7;
  const int aTile = aTilesMod ? (mTile % aTilesMod) : mTile;
  const long aRowBase = (long)aTile << 7;
  const long bOff = mTilesPerBatch ? (long)(mTile / mTilesPerBatch) * bStride : 0;

  const u16* Agh = AF16 ? nullptr : (Ah + aRowBase * ldA);
  const u16* Agl = SPLIT ? (Al + aRowBase * ldA) : nullptr;
  const u16* Bgh = Bh + bOff + (long)colBase * ldB;
  const u16* Bgl = SPLIT ? (Bl + bOff + (long)colBase * ldB) : nullptr;

  const int tid = threadIdx.x;
  const int wave = tid >> 6, lane = tid & 63;
  const int wr = wave >> 1, wc = wave & 1;
  const int sr = wave * 16 + (lane >> 2);      // staged LDS row (within 64-row half)
  const int scS = (((lane & 3) ^ ((sr >> 1) & 3)) << 3);  // swizzled global u16 col
  const int lr = lane & 15;
  const int lk = (lane >> 4) << 3;

  f32x4 acc[4][4];
#pragma unroll
  for (int m = 0; m < 4; ++m)
#pragma unroll
    for (int n = 0; n < 4; ++n) acc[m][n] = f32x4{0.f, 0.f, 0.f, 0.f};

  auto stage = [&](int buf, int k0) {
    u16* sb = smem + buf * HSM;
    if (AF16) {
      const int gk = k0 + kOff;
      const float* As = (gk < kSw) ? (Af0 + aRowBase * (long)ldA + gk)
                                   : (Af1 + aRowBase * (long)ldA + (gk - kSw));
      const int rr = tid >> 3;
#pragma unroll
      for (int i = 0; i < 4; ++i) {
        const int row = i * 32 + rr;
        const int csw = (((tid & 7) ^ (row & 7)) << 2);  // XOR-swizzled f32 col
        gload_lds16(As + (long)row * ldA + csw, &sb[i * 2048 + wave * 512]);
      }
#pragma unroll
      for (int i = 0; i < 2; ++i) {
        const long ro = (long)(i * 64 + sr) * ldB + k0 + kOff + scS;
        gload_lds16(Bgh + ro, &sb[TBH + i * 2048 + wave * 512]);
      }
    } else {
#pragma unroll
      for (int i = 0; i < 2; ++i) {
        const long roA = (long)(i * 64 + sr) * ldA + k0 + scS;
        const long roB = (long)(i * 64 + sr) * ldB + k0 + scS;
        const int lo_ = i * 2048 + wave * 512;
        gload_lds16(Agh + roA, &sb[lo_]);
        gload_lds16(Bgh + roB, &sb[TBH + lo_]);
        if (SPLIT) {
          gload_lds16(Agl + roA, &sb[TAL + lo_]);
          gload_lds16(Bgl + roB, &sb[TBL + lo_]);
        }
      }
    }
  };

  auto compute = [&](int buf) {
    const u16* sb = smem + buf * HSM;
    if (AF16) {
      f16x8 fa[4], fb[4];
      const char* smemb = (const char*)sb;
#pragma unroll
      for (int m = 0; m < 4; ++m) {
        const int row = wr * 64 + m * 16 + lr;
        const int xr = (row & 7) << 4;
        const char* rp = smemb + row * 128;
        const f32x4 p0 = *(const f32x4*)(rp + ((lk << 2) ^ xr));
        const f32x4 p1 = *(const f32x4*)(rp + (((lk << 2) + 16) ^ xr));
        f16x8 va;
        va[0] = (_Float16)p0.x; va[1] = (_Float16)p0.y;
        va[2] = (_Float16)p0.z; va[3] = (_Float16)p0.w;
        va[4] = (_Float16)p1.x; va[5] = (_Float16)p1.y;
        va[6] = (_Float16)p1.z; va[7] = (_Float16)p1.w;
        fa[m] = va;
      }
#pragma unroll
      for (int n = 0; n < 4; ++n) {
        const int row = wc * 64 + n * 16 + lr;
        const int off = row * 32 + (((lane >> 4) ^ ((row >> 1) & 3)) << 3);
        fb[n] = __builtin_bit_cast(f16x8, *(const u16x8*)&sb[TBH + off]);
      }
      __builtin_amdgcn_s_setprio(1);
#pragma unroll
      for (int m = 0; m < 4; ++m)
#pragma unroll
        for (int n = 0; n < 4; ++n)
          acc[m][n] = __builtin_amdgcn_mfma_f32_16x16x32_f16(fa[m], fb[n], acc[m][n], 0, 0, 0);
      __builtin_amdgcn_s_setprio(0);
    } else {
      bf16x8 fah[4], fbh[4], fal[4], fbl[4];
#pragma unroll
      for (int m = 0; m < 4; ++m) {
        const int row = wr * 64 + m * 16 + lr;
        const int off = row * 32 + (((lane >> 4) ^ ((row >> 1) & 3)) << 3);
        fah[m] = __builtin_bit_cast(bf16x8, *(const u16x8*)&sb[off]);
        if (SPLIT) fal[m] = __builtin_bit_cast(bf16x8, *(const u16x8*)&sb[TAL + off]);
      }
#pragma unroll
      for (int n = 0; n < 4; ++n) {
        const int row = wc * 64 + n * 16 + lr;
        const int off = row * 32 + (((lane >> 4) ^ ((row >> 1) & 3)) << 3);
        fbh[n] = __builtin_bit_cast(bf16x8, *(const u16x8*)&sb[TBH + off]);
        if (SPLIT) fbl[n] = __builtin_bit_cast(bf16x8, *(const u16x8*)&sb[TBL + off]);
      }
#pragma unroll
      for (int m = 0; m < 4; ++m)
#pragma unroll
        for (int n = 0; n < 4; ++n) {
          acc[m][n] = __builtin_amdgcn_mfma_f32_16x16x32_bf16(fah[m], fbh[n], acc[m][n], 0, 0, 0);
          if (SPLIT) {
            acc[m][n] = __builtin_amdgcn_mfma_f32_16x16x32_bf16(fah[m], fbl[n], acc[m][n], 0, 0, 0);
            acc[m][n] = __builtin_amdgcn_mfma_f32_16x16x32_bf16(fal[m], fbh[n], acc[m][n], 0, 0, 0);
          }
        }
    }
  };

  // T4 counted-vmcnt pipeline, DEPTH buffers, 2 raw barriers/iter.
  const int nSteps = K >> 5;
  stage(0, 0);
  if (DEPTH == 3 && nSteps > 1) stage(1, 32);
  for (int t = 0; t < nSteps; ++t) {
    const int cur = t % DEPTH;
    if (t + DEPTH - 1 < nSteps) {
      stage((t + DEPTH - 1) % DEPTH, (t + DEPTH - 1) << 5);
      vmwait<LPS * (DEPTH - 1)>();           // batch t landed; newer stay in flight
    } else if (DEPTH == 3 && t + 1 < nSteps) {
      vmwait<LPS>();                         // one batch still in flight
    } else {
      vmwait<0>();                           // final drain
    }
    __builtin_amdgcn_s_barrier();            // all waves' batch-t in LDS
    __builtin_amdgcn_sched_barrier(0);       // no ds_read hoist above (rule 18)
    compute(cur);
    __builtin_amdgcn_sched_barrier(0);       // no ds_read sink below
    __builtin_amdgcn_s_barrier();            // readers done before overwrite
  }

  const int rloc = (lane >> 4) << 2;
  float* o3 = (float*)(half ? out2 : out1);
#pragma unroll
  for (int m = 0; m < 4; ++m) {
#pragma unroll
    for (int n = 0; n < 4; ++n) {
      const int col = colBase + wc * 64 + n * 16 + lr;
#pragma unroll
      for (int j = 0; j < 4; ++j) {
        const long row = rowBase + wr * 64 + m * 16 + rloc + j;
        const float v = acc[m][n][j];
        if (EPI == 1) {
          ((float*)out1)[row * (long)ldOut + col] =
              (v + bias[col] + extra[row * 1024 + col]) * scale;
        } else if (EPI == 2) {
          ((u16*)out1)[row * (long)ldOut + col] = f2bf(v * scale);
        } else if (EPI == 3) {
          o3[row * (long)ldOut + col] = v;
        } else if (EPI == 6) {
          const _Float16 hv = (_Float16)v;  // RNE
          ((u16*)out1)[row * (long)ldOut + col] = __builtin_bit_cast(u16, hv);
        }
      }
    }
  }
}

extern "C" void kernel_launch(void* const* d_in, const int* in_sizes, int n_in,
                              void* d_out, int out_size, void* d_ws, size_t ws_size,
                              hipStream_t stream) {
  (void)in_sizes; (void)n_in; (void)out_size; (void)ws_size;
  const float* x     = (const float*)d_in[0];
  const float* we    = (const float*)d_in[1];
  const float* conv  = (const float*)d_in[2];
  const float* in_v  = (const float*)d_in[3];
  const float* in_g  = (const float*)d_in[4];
  const float* in_b  = (const float*)d_in[5];
  const float* out_v = (const float*)d_in[6];
  const float* out_g = (const float*)d_in[7];
  const float* out_b = (const float*)d_in[8];
  float* out  = (float*)d_out;
  float* attn = out + 33554432l;  // B*L*C floats, then B*L*196

  char* ws = (char*)d_ws;
  u16* bth    = (u16*)(ws);                  // y_t bf16 hi [32][256][1024]
  u16* btl    = (u16*)(ws + 16777216l);      // y_t bf16 lo
  u16* concat = (u16*)(ws + 33554432l);      // f16 [32][256][2048]: Zi | y
  u16* wth    = (u16*)(ws + 67108864l);      // Wt pair [1024][1024]
  u16* wtl    = (u16*)(ws + 69206016l);
  u16* wo     = (u16*)(ws + 71303168l);      // Wo bf16 [1024][1024]
  u16* zo     = (u16*)(ws + 73400320l);      // Zo bf16 [32][1024][256] (x14 folded)
  u16* attbf  = (u16*)(ws + 90177536l);      // [32768][256]
  float* rc   = (float*)(ws + 106954752l);   // [32][256]
  float* s1   = (float*)(ws + 109051904l);   // K-split half-1 scores [32768][256]
  float* s0   = out;                         // K-split half-0 scores in out region

  wnorm_t_kernel<<<1024, 256, 0, stream>>>(in_v, in_g, wth, wtl);
  wnorm_kernel<<<1024, 256, 0, stream>>>(out_v, out_g, wo);
  prep_y_kernel<<<512, 256, 0, stream>>>(conv, bth, btl, concat);
  rc_kernel<<<1568, 256, 0, stream>>>(in_b, bth, btl, rc);
  // Zi^T[b*256+v][c] = sum_e y_t[b][v][e] * Wt[c][e], 3-term bf16 split,
  // output SINGLE f16 into concat cols 0..1023  (M=8192, N=1024, K=1024)
  gemm128<6, 1><<<512, 256, 0, stream>>>(
      bth, btl, nullptr, nullptr, 0, wth, wtl,
      1024, 1024, 1024, 1024, 2048, 0, 0, 0, 0, nullptr, nullptr, 1.f, concat, nullptr);
  // scores = [x|we] @ [Zi;y], single-fp16 MFMA, K-split halves (grid 2x512):
  // half0: x@Zi -> s0 ; half1: we@y -> s1   (per-half K=1024; A f32->f16 in-reg)
  gemm128<3, 2><<<1024, 256, 0, stream>>>(
      nullptr, nullptr, x, we, 1024, concat, nullptr,
      256, 1024, 1024, 2048, 256, 8, 524288l, 0, 1, nullptr, nullptr, 1.f, s0, s1);
  softmax_kernel<<<8192, 256, 0, stream>>>(s0, s1, rc, attn, attbf);
  // Zo[b*1024+c][v] = 14 * sum_e Wo[c][e] * y_t[b][v][e] -> bf16
  // (M=32768, N=256, K=1024; A=Wo replicated per batch, B=y_t hi batched)
  gemm128<2, 0><<<512, 256, 0, stream>>>(
      wo, nullptr, nullptr, nullptr, 0, bth, nullptr,
      256, 1024, 1024, 1024, 256, 8, 262144l, 8, 0, nullptr, nullptr, 14.f, zo, nullptr);
  // out = (attn_bf @ Zo^T + out_b + x) * sqrt(0.5)  (M=32768, N=1024, K=256)
  gemm128<1, 0><<<2048, 256, 0, stream>>>(
      attbf, nullptr, nullptr, nullptr, 0, zo, nullptr,
      1024, 256, 256, 256, 1024, 8, 262144l, 0, 0, out_b, x, SQHF, out, nullptr);
}

// Round 10
// 302.082 us; speedup vs baseline: 1.1773x; 1.1773x over previous
//
#include <hip/hip_runtime.h>
#include <hip/hip_bf16.h>

typedef unsigned short u16;
typedef _Float16 f16x8 __attribute__((ext_vector_type(8)));
typedef unsigned short u16x8 __attribute__((ext_vector_type(8)));
typedef float f32x4 __attribute__((ext_vector_type(4)));

#define SQHF 0.70710678118654752440f

__device__ __forceinline__ u16 f2h(float f) {
  const _Float16 h = (_Float16)f;  // RNE
  return __builtin_bit_cast(u16, h);
}

template <int N>
__device__ __forceinline__ void vmwait() {
  asm volatile("s_waitcnt vmcnt(%0)" ::"i"(N) : "memory");
}

// async global->LDS, 16B per lane; LDS dest is wave-uniform base + lane*16
__device__ __forceinline__ void gload_lds16(const void* g, void* l) {
  __builtin_amdgcn_global_load_lds(
      (const __attribute__((address_space(1))) unsigned int*)g,
      (__attribute__((address_space(3))) unsigned int*)l, 16, 0, 0);
}

__device__ __forceinline__ float block_sum(float v) {
#pragma unroll
  for (int o = 32; o; o >>= 1) v += __shfl_xor(v, o);
  __shared__ float red[4];
  if ((threadIdx.x & 63) == 0) red[threadIdx.x >> 6] = v;
  __syncthreads();
  return red[0] + red[1] + red[2] + red[3];
}

// weight-norm of in_v rows (dim E over C), store TRANSPOSED f16 Wt[c][e]
__global__ void wnorm_t_kernel(const float* __restrict__ v, const float* __restrict__ g,
                               u16* __restrict__ wtf) {
  const int e = blockIdx.x;
  const float* vr = v + (long)e * 1024;
  float ss = 0.f;
  for (int c = threadIdx.x; c < 1024; c += 256) { float t = vr[c]; ss += t * t; }
  const float tot = block_sum(ss);
  const float scl = g[e] / sqrtf(tot);
  for (int c = threadIdx.x; c < 1024; c += 256) wtf[(long)c * 1024 + e] = f2h(vr[c] * scl);
}

// weight-norm of out_v rows (dim C over E), natural layout f16 (A for Zo GEMM)
__global__ void wnorm_kernel(const float* __restrict__ v, const float* __restrict__ g,
                             u16* __restrict__ w) {
  const int c = blockIdx.x;
  const float* vr = v + (long)c * 1024;
  float ss = 0.f;
  for (int e = threadIdx.x; e < 1024; e += 256) { float t = vr[e]; ss += t * t; }
  const float tot = block_sum(ss);
  const float scl = g[c] / sqrtf(tot);
  for (int e = threadIdx.x; e < 1024; e += 256) w[(long)c * 1024 + e] = f2h(vr[e] * scl);
}

// conv_feats [B,1024,196] -> y_t f16 into concat cols 1024..2047 (rows v>=196 zero)
// + rc[b][v] += sum_{e in chunk} in_b[e]*y[b,e,v] via f32 atomics (rc pre-zeroed).
__global__ void prep_y_kernel(const float* __restrict__ conv, const float* __restrict__ in_b,
                              u16* __restrict__ concat, float* __restrict__ rc) {
  const int b = blockIdx.x >> 4;
  const int e0 = (blockIdx.x & 15) << 6;
  __shared__ float tile[64 * 224];
  const float* cb = conv + ((long)b * 1024 + e0) * 196;
  for (int idx = threadIdx.x; idx < 64 * 224; idx += 256) {
    const int rr = idx / 224, vv = idx - rr * 224;
    tile[idx] = (vv < 196) ? cb[(long)rr * 196 + vv] : 0.f;
  }
  __syncthreads();
  for (int idx = threadIdx.x; idx < 256 * 64; idx += 256) {
    const int vr = idx >> 6, c = idx & 63;
    const float val = (vr < 224) ? tile[c * 224 + vr] : 0.f;
    concat[((long)b * 256 + vr) * 2048 + 1024 + e0 + c] = f2h(val);
  }
  const int v = threadIdx.x;
  if (v < 196) {
    float s = 0.f;
#pragma unroll 8
    for (int rr = 0; rr < 64; ++rr) s += in_b[e0 + rr] * tile[rr * 224 + v];
    atomicAdd(&rc[b * 256 + v], s);
  }
}

// scores = s0+s1 (K-split halves) +rc, *sqrt(1/2) -> attn f32 [M][196] + attn f16 [M][256]
__global__ void softmax_kernel(const float* __restrict__ s0b, const float* __restrict__ s1b,
                               const float* __restrict__ rc,
                               float* __restrict__ attn, u16* __restrict__ attn_f) {
  const long row = (long)blockIdx.x * 4 + (threadIdx.x >> 6);
  const int lane = threadIdx.x & 63;
  const int b = (int)(row >> 10);
  const float* s0 = s0b + row * 256;
  const float* s1 = s1b + row * 256;
  const float* rcb = rc + b * 256;
  float v0 = (s0[lane] + s1[lane] + rcb[lane]) * SQHF;
  float v1 = (s0[64 + lane] + s1[64 + lane] + rcb[64 + lane]) * SQHF;
  float v2 = (s0[128 + lane] + s1[128 + lane] + rcb[128 + lane]) * SQHF;
  float v3 = (lane < 4) ? (s0[192 + lane] + s1[192 + lane] + rcb[192 + lane]) * SQHF : -1e30f;
  float mx = fmaxf(fmaxf(v0, v1), fmaxf(v2, v3));
#pragma unroll
  for (int o = 32; o; o >>= 1) mx = fmaxf(mx, __shfl_xor(mx, o));
  const float e0 = __expf(v0 - mx), e1 = __expf(v1 - mx), e2 = __expf(v2 - mx);
  const float e3 = (lane < 4) ? __expf(v3 - mx) : 0.f;
  float sm = e0 + e1 + e2 + e3;
#pragma unroll
  for (int o = 32; o; o >>= 1) sm += __shfl_xor(sm, o);
  const float inv = 1.f / sm;
  float* arow = attn + row * 196;
  arow[lane] = e0 * inv;
  arow[64 + lane] = e1 * inv;
  arow[128 + lane] = e2 * inv;
  if (lane < 4) arow[192 + lane] = e3 * inv;
  u16* brow = attn_f + row * 256;
  brow[lane] = f2h(e0 * inv);
  brow[64 + lane] = f2h(e1 * inv);
  brow[128 + lane] = f2h(e2 * inv);
  brow[192 + lane] = (lane < 4) ? f2h(e3 * inv) : (u16)0;
}

// 128x128-tile fp16 MFMA GEMM, B^T-layout operands, T4 counted-vmcnt pipeline
// (R8-validated, DEPTH=2: per step {stage(next); vmcnt(LPS) waits only the
// batch needed NOW; s_barrier; compute; s_barrier} — no vmcnt(0) in steady
// state). R9 lesson: DEPTH=3 (72KB LDS) lost a resident block, net wash.
// MODE 2: A staged as f32 (XOR-swizzled), RNE->f16 in-register; B f16.
//         6 loads/stage, 48KB LDS.
// MODE 3: A,B both f16 from global. 4 loads/stage, 32KB LDS.
// f16 LDS tiles use chunk-XOR swizzle (row>>1)&3 on both stage-src and read.
// kSplit2: grid doubled; half=bid&1 selects K-half (kOff=half*1024), EPI3 target.
// EPI: 1=(acc+bias[col]+extra[row*ldOut+col])*scale -> f32
//      3=acc -> f32 (out1/out2 by half);  6=(_Float16)(acc*scale) -> f16
// NOTE: NO min-waves clause (R3: (256,4)->spills; R4: (256,2)->lost ILP).
template <int EPI, int MODE>
__global__ __launch_bounds__(256) void gemm128(
    const u16* __restrict__ Ah,
    const float* __restrict__ Af0, const float* __restrict__ Af1, int kSw,
    const u16* __restrict__ Bh,
    int N, int K, int ldA, int ldB, int ldOut,
    int mTilesPerBatch, long bStride, int aTilesMod, int kSplit2,
    const float* __restrict__ bias, const float* __restrict__ extra,
    float scale, void* __restrict__ out1, void* __restrict__ out2) {
  constexpr int AF32 = (MODE == 2);
  constexpr int LPS = AF32 ? 6 : 4;           // gload_lds16 per wave per stage
  constexpr int TBH = AF32 ? 8192 : 4096;     // B tile base (u16 slots)
  constexpr int HSM = AF32 ? 12288 : 8192;    // per-buffer u16 slots
  __shared__ __align__(16) u16 smem[HSM * 2];

  int bid = blockIdx.x, nwg = gridDim.x, half = 0;
  if (kSplit2) { half = bid & 1; bid >>= 1; nwg >>= 1; }
  const int kOff = half << 10;

  const int numN = N >> 7;
  const int q = nwg >> 3, r = nwg & 7, xcd = bid & 7, l8 = bid >> 3;
  const int wg = (xcd < r ? xcd * (q + 1) : r * (q + 1) + (xcd - r) * q) + l8;
  const int mTile = wg / numN, nTile = wg - mTile * numN;
  const long rowBase = (long)mTile << 7;
  const int colBase = nTile << 7;
  const int aTile = aTilesMod ? (mTile % aTilesMod) : mTile;
  const long aRowBase = (long)aTile << 7;
  const long bOff = mTilesPerBatch ? (long)(mTile / mTilesPerBatch) * bStride : 0;

  const u16* Agh = AF32 ? nullptr : (Ah + aRowBase * ldA);
  const u16* Bgh = Bh + bOff + (long)colBase * ldB;

  const int tid = threadIdx.x;
  const int wave = tid >> 6, lane = tid & 63;
  const int wr = wave >> 1, wc = wave & 1;
  const int sr = wave * 16 + (lane >> 2);      // staged LDS row (within 64-row half)
  const int scS = (((lane & 3) ^ ((sr >> 1) & 3)) << 3);  // swizzled global u16 col
  const int lr = lane & 15;
  const int lk = (lane >> 4) << 3;

  f32x4 acc[4][4];
#pragma unroll
  for (int m = 0; m < 4; ++m)
#pragma unroll
    for (int n = 0; n < 4; ++n) acc[m][n] = f32x4{0.f, 0.f, 0.f, 0.f};

  auto stage = [&](int buf, int k0) {
    u16* sb = smem + buf * HSM;
    if (AF32) {
      const int gk = k0 + kOff;
      const float* As = (gk < kSw) ? (Af0 + aRowBase * (long)ldA + gk)
                                   : (Af1 + aRowBase * (long)ldA + (gk - kSw));
      const int rr = tid >> 3;
#pragma unroll
      for (int i = 0; i < 4; ++i) {
        const int row = i * 32 + rr;
        const int csw = (((tid & 7) ^ (row & 7)) << 2);  // XOR-swizzled f32 col
        gload_lds16(As + (long)row * ldA + csw, &sb[i * 2048 + wave * 512]);
      }
#pragma unroll
      for (int i = 0; i < 2; ++i) {
        const long ro = (long)(i * 64 + sr) * ldB + k0 + kOff + scS;
        gload_lds16(Bgh + ro, &sb[TBH + i * 2048 + wave * 512]);
      }
    } else {
#pragma unroll
      for (int i = 0; i < 2; ++i) {
        const long roA = (long)(i * 64 + sr) * ldA + k0 + kOff + scS;
        const long roB = (long)(i * 64 + sr) * ldB + k0 + kOff + scS;
        const int lo_ = i * 2048 + wave * 512;
        gload_lds16(Agh + roA, &sb[lo_]);
        gload_lds16(Bgh + roB, &sb[TBH + lo_]);
      }
    }
  };

  auto compute = [&](int buf) {
    const u16* sb = smem + buf * HSM;
    f16x8 fa[4], fb[4];
    if (AF32) {
      const char* smemb = (const char*)sb;
#pragma unroll
      for (int m = 0; m < 4; ++m) {
        const int row = wr * 64 + m * 16 + lr;
        const int xr = (row & 7) << 4;
        const char* rp = smemb + row * 128;
        const f32x4 p0 = *(const f32x4*)(rp + ((lk << 2) ^ xr));
        const f32x4 p1 = *(const f32x4*)(rp + (((lk << 2) + 16) ^ xr));
        f16x8 va;
        va[0] = (_Float16)p0.x; va[1] = (_Float16)p0.y;
        va[2] = (_Float16)p0.z; va[3] = (_Float16)p0.w;
        va[4] = (_Float16)p1.x; va[5] = (_Float16)p1.y;
        va[6] = (_Float16)p1.z; va[7] = (_Float16)p1.w;
        fa[m] = va;
      }
    } else {
#pragma unroll
      for (int m = 0; m < 4; ++m) {
        const int row = wr * 64 + m * 16 + lr;
        const int off = row * 32 + (((lane >> 4) ^ ((row >> 1) & 3)) << 3);
        fa[m] = __builtin_bit_cast(f16x8, *(const u16x8*)&sb[off]);
      }
    }
#pragma unroll
    for (int n = 0; n < 4; ++n) {
      const int row = wc * 64 + n * 16 + lr;
      const int off = row * 32 + (((lane >> 4) ^ ((row >> 1) & 3)) << 3);
      fb[n] = __builtin_bit_cast(f16x8, *(const u16x8*)&sb[TBH + off]);
    }
    __builtin_amdgcn_s_setprio(1);
#pragma unroll
    for (int m = 0; m < 4; ++m)
#pragma unroll
      for (int n = 0; n < 4; ++n)
        acc[m][n] = __builtin_amdgcn_mfma_f32_16x16x32_f16(fa[m], fb[n], acc[m][n], 0, 0, 0);
    __builtin_amdgcn_s_setprio(0);
  };

  // T4 counted-vmcnt pipeline, 2 buffers, 2 raw barriers/iter.
  const int nSteps = K >> 5;
  stage(0, 0);
  for (int t = 0; t < nSteps; ++t) {
    const int cur = t & 1;
    if (t + 1 < nSteps) {
      stage(cur ^ 1, (t + 1) << 5);          // LPS new loads in flight
      vmwait<LPS>();                         // batch t landed
    } else {
      vmwait<0>();                           // final drain
    }
    __builtin_amdgcn_s_barrier();            // all waves' batch-t in LDS
    __builtin_amdgcn_sched_barrier(0);       // no ds_read hoist above (rule 18)
    compute(cur);
    __builtin_amdgcn_sched_barrier(0);       // no ds_read sink below
    __builtin_amdgcn_s_barrier();            // readers done before overwrite
  }

  const int rloc = (lane >> 4) << 2;
  float* o3 = (float*)(half ? out2 : out1);
#pragma unroll
  for (int m = 0; m < 4; ++m) {
#pragma unroll
    for (int n = 0; n < 4; ++n) {
      const int col = colBase + wc * 64 + n * 16 + lr;
#pragma unroll
      for (int j = 0; j < 4; ++j) {
        const long row = rowBase + wr * 64 + m * 16 + rloc + j;
        const float v = acc[m][n][j];
        if (EPI == 1) {
          ((float*)out1)[row * (long)ldOut + col] =
              (v + bias[col] + extra[row * (long)ldOut + col]) * scale;
        } else if (EPI == 3) {
          o3[row * (long)ldOut + col] = v;
        } else if (EPI == 6) {
          ((u16*)out1)[row * (long)ldOut + col] = f2h(v * scale);
        }
      }
    }
  }
}

extern "C" void kernel_launch(void* const* d_in, const int* in_sizes, int n_in,
                              void* d_out, int out_size, void* d_ws, size_t ws_size,
                              hipStream_t stream) {
  (void)in_sizes; (void)n_in; (void)out_size; (void)ws_size;
  const float* x     = (const float*)d_in[0];
  const float* we    = (const float*)d_in[1];
  const float* conv  = (const float*)d_in[2];
  const float* in_v  = (const float*)d_in[3];
  const float* in_g  = (const float*)d_in[4];
  const float* in_b  = (const float*)d_in[5];
  const float* out_v = (const float*)d_in[6];
  const float* out_g = (const float*)d_in[7];
  const float* out_b = (const float*)d_in[8];
  float* out  = (float*)d_out;
  float* attn = out + 33554432l;  // B*L*C floats, then B*L*196

  char* ws = (char*)d_ws;
  u16* concat = (u16*)(ws);                  // f16 [32][256][2048]: cols 0..1023 Zi | 1024.. y
  u16* wtf    = (u16*)(ws + 33554432l);      // Wt f16 [1024][1024] (transposed Wi)
  u16* wo     = (u16*)(ws + 35651584l);      // Wo f16 [1024][1024]
  u16* zo     = (u16*)(ws + 37748736l);      // Zo f16 [32][1024][256] (x14 folded)
  u16* attf   = (u16*)(ws + 54525952l);      // attn f16 [32768][256]
  float* rc   = (float*)(ws + 71303168l);    // [32][256]
  float* s1   = (float*)(ws + 71368704l);    // K-split half-1 scores [32768][256]
  float* s0   = out;                         // K-split half-0 scores in out region

  hipMemsetAsync(rc, 0, 32 * 256 * sizeof(float), stream);
  wnorm_t_kernel<<<1024, 256, 0, stream>>>(in_v, in_g, wtf);
  wnorm_kernel<<<1024, 256, 0, stream>>>(out_v, out_g, wo);
  prep_y_kernel<<<512, 256, 0, stream>>>(conv, in_b, concat, rc);
  // Zi^T[b*256+v][c] = sum_e y[b][v][e] * Wt[c][e], single-f16 MFMA,
  // A = y half of concat, out f16 into concat cols 0..1023 (M=8192,N=1024,K=1024)
  gemm128<6, 3><<<512, 256, 0, stream>>>(
      concat + 1024, nullptr, nullptr, 0, wtf,
      1024, 1024, 2048, 1024, 2048, 0, 0, 0, 0, nullptr, nullptr, 1.f, concat, nullptr);
  // scores = [x|we] @ [Zi;y], f16 MFMA, K-split halves (grid 2x512):
  // half0: x@Zi -> s0 ; half1: we@y -> s1  (per-half K=1024; A f32->f16 in-reg)
  gemm128<3, 2><<<1024, 256, 0, stream>>>(
      nullptr, x, we, 1024, concat,
      256, 1024, 1024, 2048, 256, 8, 524288l, 0, 1, nullptr, nullptr, 1.f, s0, s1);
  softmax_kernel<<<8192, 256, 0, stream>>>(s0, s1, rc, attn, attf);
  // Zo[b*1024+c][v] = 14 * sum_e Wo[c][e] * y[b][v][e] -> f16
  // (M=32768,N=256,K=1024; A=Wo replicated per batch, B=y half of concat batched)
  gemm128<6, 3><<<512, 256, 0, stream>>>(
      wo, nullptr, nullptr, 0, concat + 1024,
      256, 1024, 1024, 2048, 256, 8, 524288l, 8, 0, nullptr, nullptr, 14.f, zo, nullptr);
  // out = (attf @ Zo^T + out_b + x) * sqrt(0.5)  (M=32768, N=1024, K=256)
  gemm128<1, 3><<<2048, 256, 0, stream>>>(
      attf, nullptr, nullptr, 0, zo,
      1024, 256, 256, 256, 1024, 8, 262144l, 0, 0, out_b, x, SQHF, out, nullptr);
}